// Round 7
// baseline (258.305 us; speedup 1.0000x reference)
//
#include <hip/hip_runtime.h>
#include <hip/hip_bf16.h>

#define B_ 8
#define L_ 2048
#define D_ 256
#define BK 32
#define KSPLIT 4
#define KQ (L_/KSPLIT)         // 512 keys per split
#define NIT (KQ/BK)            // 16 iterations
#define PSTR 40
#define NROW (B_*L_)           // 16384
#define NE ((size_t)B_*L_*D_)  // 4194304

typedef __attribute__((ext_vector_type(8))) _Float16 f16x8;
typedef __attribute__((ext_vector_type(4))) _Float16 hf4;
typedef __attribute__((ext_vector_type(4))) float f32x4;

#define MFMA16F(a,b,c) __builtin_amdgcn_mfma_f32_16x16x32_f16((a),(b),(c),0,0,0)
#define NEG_INF (-__builtin_inff())
#define GLL(src,dst) __builtin_amdgcn_global_load_lds( \
    (const __attribute__((address_space(1))) void*)(src), \
    (__attribute__((address_space(3))) void*)(dst), 16, 0, 0)

__device__ __forceinline__ f32x4 fmax4(f32x4 a, f32x4 b){
  f32x4 r;
  r[0]=fmaxf(a[0],b[0]); r[1]=fmaxf(a[1],b[1]);
  r[2]=fmaxf(a[2],b[2]); r[3]=fmaxf(a[3],b[3]);
  return r;
}

// ---- prep: fp32 x -> fp16 x16 (row-major) + vtl (pre-tiled swizzled V^T) ----
__global__ void prep_k(const float* __restrict__ x,
                       _Float16* __restrict__ x16,
                       _Float16* __restrict__ vtl){
  __shared__ _Float16 T[64][258];
  const int t = threadIdx.x;
  const int l0 = blockIdx.x*64, b = blockIdx.y;
  const int r = t>>5, c = (t&31)*8;
  #pragma unroll
  for (int p=0;p<8;++p){
    int row = r + p*8;
    size_t idx = ((size_t)(b*L_ + l0 + row))*D_ + c;
    float4 v0 = *(const float4*)(x + idx);
    float4 v1 = *(const float4*)(x + idx + 4);
    f16x8 h;
    h[0]=(_Float16)v0.x; h[1]=(_Float16)v0.y; h[2]=(_Float16)v0.z; h[3]=(_Float16)v0.w;
    h[4]=(_Float16)v1.x; h[5]=(_Float16)v1.y; h[6]=(_Float16)v1.z; h[7]=(_Float16)v1.w;
    *(f16x8*)(x16 + idx) = h;
    #pragma unroll
    for (int j=0;j<8;++j) T[row][c+j] = h[j];
  }
  __syncthreads();
  _Float16* vb = vtl + ((size_t)(b*64 + blockIdx.x*2))*8192;
  #pragma unroll
  for (int i=0;i<8;++i){
    int n = t + 256*i;
    int q = n & 1023, tile = n>>10;
    int d = q>>2, ph = q&3;
    int kc = ph ^ ((d>>1)&3);
    int k0 = tile*32 + kc*8;
    f16x8 h;
    #pragma unroll
    for (int j=0;j<8;++j) h[j] = T[k0+j][d];
    *(f16x8*)(vb + (size_t)n*8) = h;
  }
}

// ---- pass A: per-row max of masked/diag'ed scores over one key-split ----
// Identical MFMA arithmetic to flash_k => its max is an exact upper bound.
__launch_bounds__(256, 2)
__global__ void rowmax_k(const _Float16* __restrict__ x16,
                         const int* __restrict__ mask,
                         float* __restrict__ pmax){
  __shared__ __attribute__((aligned(16))) _Float16 sK[2][8192];   // 2 x 16 KB

  const int tid  = threadIdx.x;
  const int wave = tid >> 6, lane = tid & 63;
  const int quad = lane >> 4, l16 = lane & 15;
  const int b = blockIdx.y, z = blockIdx.z;
  const int q0w = blockIdx.x*128 + wave*32;
  const int sw = l16 & 7;

  f16x8 qh[2][8];
  #pragma unroll
  for (int rs=0; rs<2; ++rs){
    const _Float16* qr = x16 + ((size_t)(b*L_ + q0w + rs*16 + l16))*D_;
    #pragma unroll
    for (int ks=0; ks<8; ++ks)
      qh[rs][ks] = *(const f16x8*)(qr + ks*32 + quad*8);
  }
  unsigned mb = 0;
  {
    const int* mrow = mask + b*L_ + z*KQ;
    #pragma unroll
    for (int j=0;j<32;++j) mb |= (mrow[j*16 + l16] ? 1u : 0u) << j;
  }

  unsigned kof[4], dof[4];
  #pragma unroll
  for (int i=0;i<4;++i){
    int c = (wave + i*4)*64 + lane;
    int r = c>>5, pk = c&31;
    kof[i] = (unsigned)(r*512 + ((pk ^ (r&7))*16));
    dof[i] = (unsigned)((wave + i*4)*1024);
  }
  const char* kbase = (const char*)x16 + ((size_t)b*L_ + (size_t)z*KQ)*(D_*2);
  #pragma unroll
  for (int i=0;i<4;++i) GLL(kbase + kof[i], (char*)sK[0] + dof[i]);

  f32x4 macc[2] = {(f32x4){NEG_INF,NEG_INF,NEG_INF,NEG_INF},
                   (f32x4){NEG_INF,NEG_INF,NEG_INF,NEG_INF}};
  __syncthreads();

  for (int it=0; it<NIT; ++it){
    if (it+1 < NIT){
      const char* kb2 = kbase + (size_t)(it+1)*16384;
      char* kd = (char*)sK[(it+1)&1];
      #pragma unroll
      for (int i=0;i<4;++i) GLL(kb2 + kof[i], kd + dof[i]);
    }
    const _Float16* kb = sK[it&1];

    f32x4 S[2][2];
    S[0][0]=(f32x4){0,0,0,0}; S[0][1]=(f32x4){0,0,0,0};
    S[1][0]=(f32x4){0,0,0,0}; S[1][1]=(f32x4){0,0,0,0};
    #pragma unroll
    for (int ks=0; ks<8; ++ks){
      f16x8 b0 = *(const f16x8*)(kb + (     l16)*256 + (((ks*4+quad)^sw)*8));
      f16x8 b1 = *(const f16x8*)(kb + (16 + l16)*256 + (((ks*4+quad)^sw)*8));
      S[0][0] = MFMA16F(qh[0][ks], b0, S[0][0]);
      S[0][1] = MFMA16F(qh[0][ks], b1, S[0][1]);
      S[1][0] = MFMA16F(qh[1][ks], b0, S[1][0]);
      S[1][1] = MFMA16F(qh[1][ks], b1, S[1][1]);
    }
    // diag zero (alignment => d0 in {0,16} when present)
    #pragma unroll
    for (int rs=0; rs<2; ++rs){
      const int d0 = q0w + rs*16 - (z*KQ + it*BK);
      if ((unsigned)d0 < 32u){
        const int ntd = d0 >> 4;
        #pragma unroll
        for (int r=0;r<4;++r)
          S[rs][ntd][r] = (l16 == quad*4+r) ? 0.0f : S[rs][ntd][r];
      }
    }
    // key padding mask
    #pragma unroll
    for (int nt=0; nt<2; ++nt){
      const float mk = ((mb >> (unsigned)(it*2+nt)) & 1u) ? NEG_INF : 0.0f;
      #pragma unroll
      for (int r=0;r<4;++r){ S[0][nt][r] += mk; S[1][nt][r] += mk; }
    }
    macc[0] = fmax4(macc[0], fmax4(S[0][0], S[0][1]));
    macc[1] = fmax4(macc[1], fmax4(S[1][0], S[1][1]));

    __syncthreads();
  }

  // cross-lane max over the 16 cols, then write per-row partial max
  #pragma unroll
  for (int rs=0; rs<2; ++rs){
    f32x4 t = macc[rs];
    #pragma unroll
    for (int off=1; off<16; off<<=1){
      f32x4 o;
      o[0]=__shfl_xor(t[0],off); o[1]=__shfl_xor(t[1],off);
      o[2]=__shfl_xor(t[2],off); o[3]=__shfl_xor(t[3],off);
      t = fmax4(t,o);
    }
    if (l16 == 0){
      const int row = b*L_ + q0w + rs*16 + quad*4;
      #pragma unroll
      for (int r=0;r<4;++r) pmax[z*NROW + row + r] = t[r];
    }
  }
}

// ---- pass B: flash with FIXED per-row max (no online rescale at all) ----
__launch_bounds__(256, 2)
__global__ void flash_k(const _Float16* __restrict__ x16,
                        const _Float16* __restrict__ vtl,
                        const int* __restrict__ mask,
                        const float* __restrict__ pmax,
                        _Float16* __restrict__ oall,
                        float* __restrict__ mll){
  __shared__ __attribute__((aligned(16))) _Float16 sK[2][8192];   // 32 KB
  __shared__ __attribute__((aligned(16))) _Float16 sV[2][8192];   // 32 KB
  __shared__ __attribute__((aligned(16))) _Float16 sP[4][32*PSTR];// 10 KB

  const int tid  = threadIdx.x;
  const int wave = tid >> 6, lane = tid & 63;
  const int quad = lane >> 4, l16 = lane & 15;
  const int b = blockIdx.y, z = blockIdx.z;
  const int q0w = blockIdx.x*128 + wave*32;
  const int sw = l16 & 7, vsw = (l16>>1)&3;

  f16x8 qh[2][8];
  #pragma unroll
  for (int rs=0; rs<2; ++rs){
    const _Float16* qr = x16 + ((size_t)(b*L_ + q0w + rs*16 + l16))*D_;
    #pragma unroll
    for (int ks=0; ks<8; ++ks)
      qh[rs][ks] = *(const f16x8*)(qr + ks*32 + quad*8);
  }
  unsigned mb = 0;
  {
    const int* mrow = mask + b*L_ + z*KQ;
    #pragma unroll
    for (int j=0;j<32;++j) mb |= (mrow[j*16 + l16] ? 1u : 0u) << j;
  }

  // global row max M (over all splits), guarded against -inf
  f32x4 M[2];
  #pragma unroll
  for (int rs=0; rs<2; ++rs){
    const int row0 = b*L_ + q0w + rs*16 + quad*4;
    f32x4 m = (f32x4){-1.0e30f,-1.0e30f,-1.0e30f,-1.0e30f};
    #pragma unroll
    for (int zc=0; zc<KSPLIT; ++zc)
      m = fmax4(m, *(const f32x4*)(pmax + zc*NROW + row0));
    M[rs] = m;
  }

  unsigned kof[4], vof[4], dof[4];
  #pragma unroll
  for (int i=0;i<4;++i){
    int c = (wave + i*4)*64 + lane;
    int r = c>>5, pk = c&31;
    kof[i] = (unsigned)(r*512 + ((pk ^ (r&7))*16));
    vof[i] = (unsigned)(c*16);
    dof[i] = (unsigned)((wave + i*4)*1024);
  }
  const char* kbase = (const char*)x16 + ((size_t)b*L_ + (size_t)z*KQ)*(D_*2);
  const char* vbase = (const char*)vtl + ((size_t)(b*64 + z*16))*16384;

  #pragma unroll
  for (int i=0;i<4;++i){
    GLL(kbase + kof[i], (char*)sK[0] + dof[i]);
    GLL(vbase + vof[i], (char*)sV[0] + dof[i]);
  }

  f32x4 O[2][16], Osum[2];
  #pragma unroll
  for (int rs=0; rs<2; ++rs){
    #pragma unroll
    for (int i=0;i<16;i++) O[rs][i] = (f32x4){0.f,0.f,0.f,0.f};
    Osum[rs] = (f32x4){0.f,0.f,0.f,0.f};
  }
  f16x8 ones;
  #pragma unroll
  for (int j=0;j<8;++j) ones[j] = (_Float16)1.0f;

  __syncthreads();   // tile 0 visible

  for (int it=0; it<NIT; ++it){
    if (it+1 < NIT){
      const char* kb2 = kbase + (size_t)(it+1)*16384;
      const char* vb2 = vbase + (size_t)(it+1)*16384;
      char* kd = (char*)sK[(it+1)&1];
      char* vd = (char*)sV[(it+1)&1];
      #pragma unroll
      for (int i=0;i<4;++i){
        GLL(kb2 + kof[i], kd + dof[i]);
        GLL(vb2 + vof[i], vd + dof[i]);
      }
    }
    const _Float16* kb = sK[it&1];
    const _Float16* vb = sV[it&1];

    // ---- S = Q·K^T ----
    f32x4 S[2][2];
    S[0][0]=(f32x4){0,0,0,0}; S[0][1]=(f32x4){0,0,0,0};
    S[1][0]=(f32x4){0,0,0,0}; S[1][1]=(f32x4){0,0,0,0};
    #pragma unroll
    for (int ks=0; ks<8; ++ks){
      f16x8 b0 = *(const f16x8*)(kb + (     l16)*256 + (((ks*4+quad)^sw)*8));
      f16x8 b1 = *(const f16x8*)(kb + (16 + l16)*256 + (((ks*4+quad)^sw)*8));
      S[0][0] = MFMA16F(qh[0][ks], b0, S[0][0]);
      S[0][1] = MFMA16F(qh[0][ks], b1, S[0][1]);
      S[1][0] = MFMA16F(qh[1][ks], b0, S[1][0]);
      S[1][1] = MFMA16F(qh[1][ks], b1, S[1][1]);
    }

    // ---- diag zero, then mask ----
    #pragma unroll
    for (int rs=0; rs<2; ++rs){
      const int d0 = q0w + rs*16 - (z*KQ + it*BK);
      if ((unsigned)d0 < 32u){
        const int ntd = d0 >> 4;
        #pragma unroll
        for (int r=0;r<4;++r)
          S[rs][ntd][r] = (l16 == quad*4+r) ? 0.0f : S[rs][ntd][r];
      }
    }
    #pragma unroll
    for (int nt=0; nt<2; ++nt){
      const float mk = ((mb >> (unsigned)(it*2+nt)) & 1u) ? NEG_INF : 0.0f;
      #pragma unroll
      for (int r=0;r<4;++r){ S[0][nt][r] += mk; S[1][nt][r] += mk; }
    }

    // ---- P = exp(S - M): no rescale, no tree, P <= 1 by construction ----
    #pragma unroll
    for (int rs=0; rs<2; ++rs)
      #pragma unroll
      for (int r=0;r<4;++r){
        const int row = rs*16 + quad*4 + r;
        sP[wave][row*PSTR +      l16] = (_Float16)__expf(S[rs][0][r] - M[rs][r]);
        sP[wave][row*PSTR + 16 + l16] = (_Float16)__expf(S[rs][1][r] - M[rs][r]);
      }
    __threadfence_block();
    f16x8 pf0 = *(const f16x8*)(&sP[wave][(     l16)*PSTR + quad*8]);
    f16x8 pf1 = *(const f16x8*)(&sP[wave][(16 + l16)*PSTR + quad*8]);

    // ---- O += P·V ; l += row-sum via ones-MFMA ----
    #pragma unroll
    for (int vt=0; vt<16; ++vt){
      f16x8 bv = *(const f16x8*)(vb + (vt*16+l16)*32 + ((quad^vsw)*8));
      O[0][vt] = MFMA16F(pf0, bv, O[0][vt]);
      O[1][vt] = MFMA16F(pf1, bv, O[1][vt]);
    }
    Osum[0] = MFMA16F(pf0, ones, Osum[0]);
    Osum[1] = MFMA16F(pf1, ones, Osum[1]);

    __syncthreads();   // buffer reuse safe + next-tile staging drained
  }

  // ---- epilogue: fragment-major fp16 partial O' + partial l ----
  #pragma unroll
  for (int rs=0; rs<2; ++rs){
    const int u = ((b*16 + blockIdx.x)*4 + wave)*2 + rs;   // == natural row/16
    _Float16* ob = oall + (size_t)z*NE + (size_t)u*4096;
    #pragma unroll
    for (int vt=0; vt<16; ++vt){
      hf4 hh;
      #pragma unroll
      for (int r=0;r<4;++r) hh[r] = (_Float16)O[rs][vt][r];
      *(hf4*)(ob + vt*256 + lane*4) = hh;
    }
    if (l16 == 0){
      const int row = u*16 + quad*4;
      #pragma unroll
      for (int r=0;r<4;++r) mll[z*NROW + row + r] = Osum[rs][r];
    }
  }
}

// ---- combine: out = (sum_z O'_z) / (sum_z l_z), coalesced both ways ----
__global__ void combine_k(float* __restrict__ out,
                          const _Float16* __restrict__ oall,
                          const float* __restrict__ mll){
  __shared__ float T2[16][260];
  const int t = threadIdx.x, u = blockIdx.x;
  const int quad = (t>>4)&3, l16 = t&15;
  const int row0 = u*16 + quad*4;

  f32x4 den = (f32x4){0.f,0.f,0.f,0.f};
  #pragma unroll
  for (int zc=0; zc<KSPLIT; ++zc)
    den += *(const f32x4*)(mll + zc*NROW + row0);
  float inv[4];
  #pragma unroll
  for (int r=0;r<4;++r) inv[r] = 1.0f/den[r];

  #pragma unroll
  for (int i=0;i<4;++i){
    const int f = t + 256*i;
    const int vt = f>>6;
    float acc[4] = {0.f,0.f,0.f,0.f};
    #pragma unroll
    for (int zc=0; zc<KSPLIT; ++zc){
      hf4 v = *(const hf4*)(oall + (size_t)zc*NE + (size_t)u*4096 + (size_t)f*4);
      #pragma unroll
      for (int r=0;r<4;++r) acc[r] += (float)v[r];
    }
    #pragma unroll
    for (int r=0;r<4;++r) T2[quad*4+r][vt*16+l16] = acc[r]*inv[r];
  }
  __syncthreads();
  #pragma unroll
  for (int p=0;p<4;++p){
    const int row = (t>>6) + p*4, col = (t&63)*4;
    float4 vv = *(const float4*)&T2[row][col];
    *(float4*)(out + ((size_t)u*16 + row)*D_ + col) = vv;
  }
}

extern "C" void kernel_launch(void* const* d_in, const int* in_sizes, int n_in,
                              void* d_out, int out_size, void* d_ws, size_t ws_size,
                              hipStream_t stream) {
  const float* x    = (const float*)d_in[0];
  const int*   mask = (const int*)d_in[1];
  float*       out  = (float*)d_out;

  _Float16* x16  = (_Float16*)d_ws;
  _Float16* vtl  = x16 + NE;
  _Float16* oall = vtl + NE;                       // KSPLIT*NE fp16
  float*    mll  = (float*)(oall + (size_t)KSPLIT*NE);
  float*    pmax = mll + (size_t)KSPLIT*NROW;      // total ~51 MB

  prep_k   <<<dim3(L_/64, B_), dim3(256), 0, stream>>>(x, x16, vtl);
  rowmax_k <<<dim3(L_/128, B_, KSPLIT), dim3(256), 0, stream>>>(x16, mask, pmax);
  flash_k  <<<dim3(L_/128, B_, KSPLIT), dim3(256), 0, stream>>>(x16, vtl, mask, pmax, oall, mll);
  combine_k<<<dim3(NROW/16), dim3(256), 0, stream>>>(out, oall, mll);
}

// Round 8
// 159.441 us; speedup vs baseline: 1.6201x; 1.6201x over previous
//
#include <hip/hip_runtime.h>
#include <hip/hip_bf16.h>

#define B_ 8
#define L_ 2048
#define D_ 256
#define BK 32
#define KSPLIT 2
#define KQ (L_/KSPLIT)         // 1024 keys per split
#define NIT (KQ/BK)            // 32 iterations
#define PSTR 40
#define NROW (B_*L_)           // 16384
#define NE ((size_t)B_*L_*D_)  // 4194304

typedef __attribute__((ext_vector_type(8))) _Float16 f16x8;
typedef __attribute__((ext_vector_type(4))) _Float16 hf4;
typedef __attribute__((ext_vector_type(4))) float f32x4;

#define MFMA16F(a,b,c) __builtin_amdgcn_mfma_f32_16x16x32_f16((a),(b),(c),0,0,0)
#define NEG_INF (-__builtin_inff())
#define GLL(src,dst) __builtin_amdgcn_global_load_lds( \
    (const __attribute__((address_space(1))) void*)(src), \
    (__attribute__((address_space(3))) void*)(dst), 16, 0, 0)

__device__ __forceinline__ f32x4 fmax4(f32x4 a, f32x4 b){
  f32x4 r;
  r[0]=fmaxf(a[0],b[0]); r[1]=fmaxf(a[1],b[1]);
  r[2]=fmaxf(a[2],b[2]); r[3]=fmaxf(a[3],b[3]);
  return r;
}

// ---- prep: fp32 x -> fp16 x16 (row-major) + vtl (pre-tiled swizzled V^T) ----
__global__ void prep_k(const float* __restrict__ x,
                       _Float16* __restrict__ x16,
                       _Float16* __restrict__ vtl){
  __shared__ _Float16 T[64][258];
  const int t = threadIdx.x;
  const int l0 = blockIdx.x*64, b = blockIdx.y;
  const int r = t>>5, c = (t&31)*8;
  #pragma unroll
  for (int p=0;p<8;++p){
    int row = r + p*8;
    size_t idx = ((size_t)(b*L_ + l0 + row))*D_ + c;
    float4 v0 = *(const float4*)(x + idx);
    float4 v1 = *(const float4*)(x + idx + 4);
    f16x8 h;
    h[0]=(_Float16)v0.x; h[1]=(_Float16)v0.y; h[2]=(_Float16)v0.z; h[3]=(_Float16)v0.w;
    h[4]=(_Float16)v1.x; h[5]=(_Float16)v1.y; h[6]=(_Float16)v1.z; h[7]=(_Float16)v1.w;
    *(f16x8*)(x16 + idx) = h;
    #pragma unroll
    for (int j=0;j<8;++j) T[row][c+j] = h[j];
  }
  __syncthreads();
  _Float16* vb = vtl + ((size_t)(b*64 + blockIdx.x*2))*8192;
  #pragma unroll
  for (int i=0;i<8;++i){
    int n = t + 256*i;
    int q = n & 1023, tile = n>>10;
    int d = q>>2, ph = q&3;
    int kc = ph ^ ((d>>1)&3);
    int k0 = tile*32 + kc*8;
    f16x8 h;
    #pragma unroll
    for (int j=0;j<8;++j) h[j] = T[k0+j][d];
    *(f16x8*)(vb + (size_t)n*8) = h;
  }
}

// ---- pass A: per-row max of masked/diag'ed scores over one key-split ----
// Same MFMA arithmetic as flash_k => exact upper bound for its exp.
__launch_bounds__(256, 2)
__global__ void rowmax_k(const _Float16* __restrict__ x16,
                         const int* __restrict__ mask,
                         float* __restrict__ pmax){
  __shared__ __attribute__((aligned(16))) _Float16 sK[2][8192];   // 32 KB

  const int tid  = threadIdx.x;
  const int wave = tid >> 6, lane = tid & 63;
  const int quad = lane >> 4, l16 = lane & 15;
  const int b = blockIdx.y, z = blockIdx.z;
  const int q0w = blockIdx.x*64 + wave*16;
  const int sw = l16 & 7;

  f16x8 qh[8];
  {
    const _Float16* qr = x16 + ((size_t)(b*L_ + q0w + l16))*D_;
    #pragma unroll
    for (int ks=0; ks<8; ++ks)
      qh[ks] = *(const f16x8*)(qr + ks*32 + quad*8);
  }
  unsigned long long mb = 0;
  {
    const int* mrow = mask + b*L_ + z*KQ;
    #pragma unroll
    for (int j=0;j<64;++j)
      mb |= (unsigned long long)(mrow[j*16 + l16] ? 1u : 0u) << j;
  }

  unsigned kof[4], dof[4];
  #pragma unroll
  for (int i=0;i<4;++i){
    int c = (wave + i*4)*64 + lane;
    int r = c>>5, pk = c&31;
    kof[i] = (unsigned)(r*512 + ((pk ^ (r&7))*16));
    dof[i] = (unsigned)((wave + i*4)*1024);
  }
  const char* kbase = (const char*)x16 + ((size_t)b*L_ + (size_t)z*KQ)*(D_*2);
  #pragma unroll
  for (int i=0;i<4;++i) GLL(kbase + kof[i], (char*)sK[0] + dof[i]);

  f32x4 macc = (f32x4){NEG_INF,NEG_INF,NEG_INF,NEG_INF};
  __syncthreads();

  for (int it=0; it<NIT; ++it){
    if (it+1 < NIT){
      const char* kb2 = kbase + (size_t)(it+1)*16384;
      char* kd = (char*)sK[(it+1)&1];
      #pragma unroll
      for (int i=0;i<4;++i) GLL(kb2 + kof[i], kd + dof[i]);
    }
    const _Float16* kb = sK[it&1];

    f32x4 S[2];
    S[0]=(f32x4){0,0,0,0}; S[1]=(f32x4){0,0,0,0};
    #pragma unroll
    for (int ks=0; ks<8; ++ks){
      f16x8 b0 = *(const f16x8*)(kb + (     l16)*256 + (((ks*4+quad)^sw)*8));
      f16x8 b1 = *(const f16x8*)(kb + (16 + l16)*256 + (((ks*4+quad)^sw)*8));
      S[0] = MFMA16F(qh[ks], b0, S[0]);
      S[1] = MFMA16F(qh[ks], b1, S[1]);
    }
    // diag zero
    {
      const int d0 = q0w - (z*KQ + it*BK);
      if ((unsigned)d0 < 32u){
        const int ntd = d0 >> 4;
        #pragma unroll
        for (int r=0;r<4;++r)
          S[ntd][r] = (l16 == quad*4+r) ? 0.0f : S[ntd][r];
      }
    }
    // key padding mask
    {
      const unsigned mw = (unsigned)(mb >> (unsigned)(it*2));
      const float mk0 = (mw & 1u) ? NEG_INF : 0.0f;
      const float mk1 = (mw & 2u) ? NEG_INF : 0.0f;
      #pragma unroll
      for (int r=0;r<4;++r){ S[0][r] += mk0; S[1][r] += mk1; }
    }
    macc = fmax4(macc, fmax4(S[0], S[1]));

    __syncthreads();
  }

  f32x4 t = macc;
  #pragma unroll
  for (int off=1; off<16; off<<=1){
    f32x4 o;
    o[0]=__shfl_xor(t[0],off); o[1]=__shfl_xor(t[1],off);
    o[2]=__shfl_xor(t[2],off); o[3]=__shfl_xor(t[3],off);
    t = fmax4(t,o);
  }
  if (l16 == 0){
    const int row = b*L_ + q0w + quad*4;
    #pragma unroll
    for (int r=0;r<4;++r) pmax[z*NROW + row + r] = t[r];
  }
}

// ---- pass B: flash with FIXED per-row max; 16 q-rows/wave (spill-free) ----
__launch_bounds__(256, 2)
__global__ void flash_k(const _Float16* __restrict__ x16,
                        const _Float16* __restrict__ vtl,
                        const int* __restrict__ mask,
                        const float* __restrict__ pmax,
                        _Float16* __restrict__ oall,
                        float* __restrict__ mll){
  __shared__ __attribute__((aligned(16))) _Float16 sK[2][8192];   // 32 KB
  __shared__ __attribute__((aligned(16))) _Float16 sV[2][8192];   // 32 KB
  __shared__ __attribute__((aligned(16))) _Float16 sP[4][16*PSTR];// 5 KB

  const int tid  = threadIdx.x;
  const int wave = tid >> 6, lane = tid & 63;
  const int quad = lane >> 4, l16 = lane & 15;
  const int b = blockIdx.y, z = blockIdx.z;
  const int q0w = blockIdx.x*64 + wave*16;
  const int sw = l16 & 7, vsw = (l16>>1)&3;

  f16x8 qh[8];
  {
    const _Float16* qr = x16 + ((size_t)(b*L_ + q0w + l16))*D_;
    #pragma unroll
    for (int ks=0; ks<8; ++ks)
      qh[ks] = *(const f16x8*)(qr + ks*32 + quad*8);
  }
  unsigned long long mb = 0;
  {
    const int* mrow = mask + b*L_ + z*KQ;
    #pragma unroll
    for (int j=0;j<64;++j)
      mb |= (unsigned long long)(mrow[j*16 + l16] ? 1u : 0u) << j;
  }

  // global row max M (over both splits)
  f32x4 M;
  {
    const int row0 = b*L_ + q0w + quad*4;
    M = fmax4(*(const f32x4*)(pmax + row0),
              *(const f32x4*)(pmax + NROW + row0));
  }

  unsigned kof[4], vof[4], dof[4];
  #pragma unroll
  for (int i=0;i<4;++i){
    int c = (wave + i*4)*64 + lane;
    int r = c>>5, pk = c&31;
    kof[i] = (unsigned)(r*512 + ((pk ^ (r&7))*16));
    vof[i] = (unsigned)(c*16);
    dof[i] = (unsigned)((wave + i*4)*1024);
  }
  const char* kbase = (const char*)x16 + ((size_t)b*L_ + (size_t)z*KQ)*(D_*2);
  const char* vbase = (const char*)vtl + ((size_t)(b*64 + z*32))*16384;

  #pragma unroll
  for (int i=0;i<4;++i){
    GLL(kbase + kof[i], (char*)sK[0] + dof[i]);
    GLL(vbase + vof[i], (char*)sV[0] + dof[i]);
  }

  f32x4 O[16], Osum;
  #pragma unroll
  for (int i=0;i<16;i++) O[i] = (f32x4){0.f,0.f,0.f,0.f};
  Osum = (f32x4){0.f,0.f,0.f,0.f};
  f16x8 ones;
  #pragma unroll
  for (int j=0;j<8;++j) ones[j] = (_Float16)1.0f;

  __syncthreads();   // tile 0 visible

  for (int it=0; it<NIT; ++it){
    if (it+1 < NIT){
      const char* kb2 = kbase + (size_t)(it+1)*16384;
      const char* vb2 = vbase + (size_t)(it+1)*16384;
      char* kd = (char*)sK[(it+1)&1];
      char* vd = (char*)sV[(it+1)&1];
      #pragma unroll
      for (int i=0;i<4;++i){
        GLL(kb2 + kof[i], kd + dof[i]);
        GLL(vb2 + vof[i], vd + dof[i]);
      }
    }
    const _Float16* kb = sK[it&1];
    const _Float16* vb = sV[it&1];

    // ---- S = Q·K^T ----
    f32x4 S[2];
    S[0]=(f32x4){0,0,0,0}; S[1]=(f32x4){0,0,0,0};
    #pragma unroll
    for (int ks=0; ks<8; ++ks){
      f16x8 b0 = *(const f16x8*)(kb + (     l16)*256 + (((ks*4+quad)^sw)*8));
      f16x8 b1 = *(const f16x8*)(kb + (16 + l16)*256 + (((ks*4+quad)^sw)*8));
      S[0] = MFMA16F(qh[ks], b0, S[0]);
      S[1] = MFMA16F(qh[ks], b1, S[1]);
    }

    // ---- diag zero, then mask ----
    {
      const int d0 = q0w - (z*KQ + it*BK);
      if ((unsigned)d0 < 32u){
        const int ntd = d0 >> 4;
        #pragma unroll
        for (int r=0;r<4;++r)
          S[ntd][r] = (l16 == quad*4+r) ? 0.0f : S[ntd][r];
      }
    }
    {
      const unsigned mw = (unsigned)(mb >> (unsigned)(it*2));
      const float mk0 = (mw & 1u) ? NEG_INF : 0.0f;
      const float mk1 = (mw & 2u) ? NEG_INF : 0.0f;
      #pragma unroll
      for (int r=0;r<4;++r){ S[0][r] += mk0; S[1][r] += mk1; }
    }

    // ---- P = exp(S - M); P <= 1 by construction ----
    #pragma unroll
    for (int r=0;r<4;++r){
      const int row = quad*4 + r;
      sP[wave][row*PSTR +      l16] = (_Float16)__expf(S[0][r] - M[r]);
      sP[wave][row*PSTR + 16 + l16] = (_Float16)__expf(S[1][r] - M[r]);
    }
    __threadfence_block();
    f16x8 pf = *(const f16x8*)(&sP[wave][l16*PSTR + quad*8]);

    // ---- O += P·V ; l += row-sum via ones-MFMA ----
    #pragma unroll
    for (int vt=0; vt<16; ++vt){
      f16x8 bv = *(const f16x8*)(vb + (vt*16+l16)*32 + ((quad^vsw)*8));
      O[vt] = MFMA16F(pf, bv, O[vt]);
    }
    Osum = MFMA16F(pf, ones, Osum);

    __syncthreads();   // buffer reuse safe + next-tile staging drained
  }

  // ---- epilogue: fragment-major fp16 partial O' + partial l ----
  {
    const int u = b*(L_/16) + blockIdx.x*4 + wave;   // natural row/16
    _Float16* ob = oall + (size_t)z*NE + (size_t)u*4096;
    #pragma unroll
    for (int vt=0; vt<16; ++vt){
      hf4 hh;
      #pragma unroll
      for (int r=0;r<4;++r) hh[r] = (_Float16)O[vt][r];
      *(hf4*)(ob + vt*256 + lane*4) = hh;
    }
    if (l16 == 0){
      const int row = u*16 + quad*4;
      #pragma unroll
      for (int r=0;r<4;++r) mll[z*NROW + row + r] = Osum[r];
    }
  }
}

// ---- combine: out = (sum_z O'_z) / (sum_z l_z), coalesced both ways ----
__global__ void combine_k(float* __restrict__ out,
                          const _Float16* __restrict__ oall,
                          const float* __restrict__ mll){
  __shared__ float T2[16][260];
  const int t = threadIdx.x, u = blockIdx.x;
  const int quad = (t>>4)&3, l16 = t&15;
  const int row0 = u*16 + quad*4;

  f32x4 den = (f32x4){0.f,0.f,0.f,0.f};
  #pragma unroll
  for (int zc=0; zc<KSPLIT; ++zc)
    den += *(const f32x4*)(mll + zc*NROW + row0);
  float inv[4];
  #pragma unroll
  for (int r=0;r<4;++r) inv[r] = 1.0f/den[r];

  #pragma unroll
  for (int i=0;i<4;++i){
    const int f = t + 256*i;
    const int vt = f>>6;
    float acc[4] = {0.f,0.f,0.f,0.f};
    #pragma unroll
    for (int zc=0; zc<KSPLIT; ++zc){
      hf4 v = *(const hf4*)(oall + (size_t)zc*NE + (size_t)u*4096 + (size_t)f*4);
      #pragma unroll
      for (int r=0;r<4;++r) acc[r] += (float)v[r];
    }
    #pragma unroll
    for (int r=0;r<4;++r) T2[quad*4+r][vt*16+l16] = acc[r]*inv[r];
  }
  __syncthreads();
  #pragma unroll
  for (int p=0;p<4;++p){
    const int row = (t>>6) + p*4, col = (t&63)*4;
    float4 vv = *(const float4*)&T2[row][col];
    *(float4*)(out + ((size_t)u*16 + row)*D_ + col) = vv;
  }
}

extern "C" void kernel_launch(void* const* d_in, const int* in_sizes, int n_in,
                              void* d_out, int out_size, void* d_ws, size_t ws_size,
                              hipStream_t stream) {
  const float* x    = (const float*)d_in[0];
  const int*   mask = (const int*)d_in[1];
  float*       out  = (float*)d_out;

  _Float16* x16  = (_Float16*)d_ws;
  _Float16* vtl  = x16 + NE;
  _Float16* oall = vtl + NE;                       // KSPLIT*NE fp16
  float*    mll  = (float*)(oall + (size_t)KSPLIT*NE);
  float*    pmax = mll + (size_t)KSPLIT*NROW;      // total ~34 MB

  prep_k   <<<dim3(L_/64, B_), dim3(256), 0, stream>>>(x, x16, vtl);
  rowmax_k <<<dim3(L_/64, B_, KSPLIT), dim3(256), 0, stream>>>(x16, mask, pmax);
  flash_k  <<<dim3(L_/64, B_, KSPLIT), dim3(256), 0, stream>>>(x16, vtl, mask, pmax, oall, mll);
  combine_k<<<dim3(NROW/16), dim3(256), 0, stream>>>(out, oall, mll);
}